// Round 3
// baseline (433.873 us; speedup 1.0000x reference)
//
#include <hip/hip_runtime.h>
#include <hip/hip_bf16.h>

// Problem constants
#define TT  1024   // sequence length T
#define NH  8      // heads H
#define NHP 16     // expanded channels HP
#define NHD 64     // head dim
#define NE  512    // embed dim
#define NB  2      // batch
// k1 tiling
#define YB  256    // y-chunk per block
#define CHX 8      // x rows per block
// k2 tiling
#define MT  16     // rows per softmax/PV block

__device__ __forceinline__ unsigned short f2bf(float f) {
    union { float f; unsigned u; } x; x.f = f;
    unsigned u = x.u;
    return (unsigned short)((u + 0x7FFFu + ((u >> 16) & 1u)) >> 16); // RNE
}
__device__ __forceinline__ float bf2f(unsigned short s) {
    union { unsigned u; float f; } x; x.u = ((unsigned)s) << 16;
    return x.f;
}

// -------------------------------------------------------------------------
// K1: fused 1x1 expand (writes A_expanded output) + depthwise 3x3 + relu
//     + 1x1 reduce * SCALE  ->  A_reduced (bf16) in workspace.
// Grid: (T/CHX, T/YB, B), 256 threads. LDS: ring of 3 expanded rows
// [3][16][YB+2] f32 = 49.5 KB -> 2 blocks/CU.
// A_expanded is stored from the stencil phase (value == center tap e1[1]),
// giving wave-aligned 256B store groups instead of the -4B-shifted halo loop.
// -------------------------------------------------------------------------
__global__ __launch_bounds__(256, 2)
void k1_fused(const float* __restrict__ A,
              const float* __restrict__ Wexp,   // [16][8]
              const float* __restrict__ Wloc,   // [16][9]
              const float* __restrict__ bloc,   // [16]
              const float* __restrict__ Wred,   // [8][16]
              float* __restrict__ Eo_all,       // A_expanded out [B][16][T][T]
              unsigned short* __restrict__ Ared)// [B][8][T][T] bf16
{
    __shared__ float Er[3][NHP][YB + 2];
    const int tid = threadIdx.x;
    const int x0 = blockIdx.x * CHX;
    const int ybase = blockIdx.y * YB;
    const int b = blockIdx.z;
    const float* Ab = A + (size_t)b * NH * TT * TT;
    float* Eo = Eo_all + (size_t)b * NHP * TT * TT;

    auto computeE = [&](int r) {
        const int slot = (r + 3072) % 3;
        for (int j = tid; j < YB + 2; j += 256) {
            const int y = ybase + j - 1;
            float e[NHP];
            if (r < 0 || r >= TT || y < 0 || y >= TT) {
                #pragma unroll
                for (int p = 0; p < NHP; ++p) e[p] = 0.f;
            } else {
                float a[NH];
                #pragma unroll
                for (int h = 0; h < NH; ++h)
                    a[h] = __builtin_nontemporal_load(
                        &Ab[((size_t)h * TT + r) * TT + y]);
                #pragma unroll
                for (int p = 0; p < NHP; ++p) {
                    float s = 0.f;
                    #pragma unroll
                    for (int h = 0; h < NH; ++h)
                        s = fmaf(Wexp[p * NH + h], a[h], s);
                    e[p] = s;
                }
            }
            #pragma unroll
            for (int p = 0; p < NHP; ++p) Er[slot][p][j] = e[p];
        }
    };

    computeE(x0 - 1);
    computeE(x0);
    __syncthreads();

    for (int x = x0; x < x0 + CHX; ++x) {
        computeE(x + 1);
        __syncthreads();
        {
            const int j = tid + 1;                       // column in [1..YB]
            const int y = ybase + tid;
            const int s0 = (x - 1 + 3072) % 3;
            const int s1 = (x + 3072) % 3;
            const int s2 = (x + 1 + 3072) % 3;
            float ar[NH];
            #pragma unroll
            for (int h = 0; h < NH; ++h) ar[h] = 0.f;
            #pragma unroll
            for (int p = 0; p < NHP; ++p) {
                float al = bloc[p];
                const float* e0 = &Er[s0][p][j - 1];
                const float* e1 = &Er[s1][p][j - 1];
                const float* e2 = &Er[s2][p][j - 1];
                al = fmaf(Wloc[p * 9 + 0], e0[0], al);
                al = fmaf(Wloc[p * 9 + 1], e0[1], al);
                al = fmaf(Wloc[p * 9 + 2], e0[2], al);
                al = fmaf(Wloc[p * 9 + 3], e1[0], al);
                al = fmaf(Wloc[p * 9 + 4], e1[1], al);
                al = fmaf(Wloc[p * 9 + 5], e1[2], al);
                al = fmaf(Wloc[p * 9 + 6], e2[0], al);
                al = fmaf(Wloc[p * 9 + 7], e2[1], al);
                al = fmaf(Wloc[p * 9 + 8], e2[2], al);
                // A_expanded output: center tap of the middle row (aligned y)
                __builtin_nontemporal_store(
                    e1[1], &Eo[((size_t)p * TT + x) * TT + y]);
                al = fmaxf(al, 0.f);
                #pragma unroll
                for (int h = 0; h < NH; ++h)
                    ar[h] = fmaf(Wred[h * NHP + p], al, ar[h]);
            }
            #pragma unroll
            for (int h = 0; h < NH; ++h)
                Ared[(((size_t)b * NH + h) * TT + x) * TT + y] =
                    f2bf(ar[h] * 0.125f);   // SCALE = 64^-0.5
        }
        __syncthreads();   // protect ring slot reuse
    }
}

// -------------------------------------------------------------------------
// K2: row softmax (wave per row) + PV: out_pre[b, t, h*64+d]
// Grid: (T/MT, H, B), 256 threads. LDS: unnormalized exp tile [16][1024] f32
// = 64 KB; per-row 1/sum kept in LDS[16] and applied in the PV epilogue.
// -------------------------------------------------------------------------
__global__ __launch_bounds__(256, 2)
void k2_softmax_pv(const unsigned short* __restrict__ Ared,
                   const float* __restrict__ V,     // [B][H][T][64]
                   float* __restrict__ Opre)        // [B][T][E]
{
    __shared__ float tile[MT][TT];
    __shared__ float rinv[MT];
    const int tid = threadIdx.x;
    const int lane = tid & 63;
    const int w = tid >> 6;
    const int x0 = blockIdx.x * MT;
    const int h = blockIdx.y;
    const int b = blockIdx.z;
    const unsigned short* Ab = Ared + (((size_t)b * NH + h) * TT + x0) * TT;

    for (int m = w; m < MT; m += 4) {
        const unsigned short* src = Ab + (size_t)m * TT;
        float vals[16];
        float mx = -3.0e38f;
        #pragma unroll
        for (int c = 0; c < 4; ++c) {
            ushort4 u = *(const ushort4*)(src + c * 256 + lane * 4);
            vals[c * 4 + 0] = bf2f(u.x);
            vals[c * 4 + 1] = bf2f(u.y);
            vals[c * 4 + 2] = bf2f(u.z);
            vals[c * 4 + 3] = bf2f(u.w);
        }
        #pragma unroll
        for (int i = 0; i < 16; ++i) mx = fmaxf(mx, vals[i]);
        #pragma unroll
        for (int off = 32; off > 0; off >>= 1)
            mx = fmaxf(mx, __shfl_xor(mx, off, 64));
        float sum = 0.f;
        #pragma unroll
        for (int i = 0; i < 16; ++i) {
            vals[i] = __expf(vals[i] - mx);
            sum += vals[i];
        }
        #pragma unroll
        for (int off = 32; off > 0; off >>= 1)
            sum += __shfl_xor(sum, off, 64);
        if (lane == 0) rinv[m] = 1.f / sum;
        #pragma unroll
        for (int c = 0; c < 4; ++c) {
            float4 st = make_float4(vals[c * 4 + 0], vals[c * 4 + 1],
                                    vals[c * 4 + 2], vals[c * 4 + 3]);
            *(float4*)&tile[m][c * 256 + lane * 4] = st;
        }
    }
    __syncthreads();

    // PV: thread = (wave -> 4 rows, lane -> output dim d)
    const int d = lane;
    const int mb = w * 4;
    const float* Vb = V + ((size_t)b * NH + h) * TT * NHD;
    float acc0 = 0.f, acc1 = 0.f, acc2 = 0.f, acc3 = 0.f;
    for (int y = 0; y < TT; y += 4) {
        float4 t0 = *(const float4*)&tile[mb + 0][y];
        float4 t1 = *(const float4*)&tile[mb + 1][y];
        float4 t2 = *(const float4*)&tile[mb + 2][y];
        float4 t3 = *(const float4*)&tile[mb + 3][y];
        float v0 = Vb[(size_t)(y + 0) * NHD + d];
        float v1 = Vb[(size_t)(y + 1) * NHD + d];
        float v2 = Vb[(size_t)(y + 2) * NHD + d];
        float v3 = Vb[(size_t)(y + 3) * NHD + d];
        acc0 = fmaf(t0.x, v0, acc0); acc0 = fmaf(t0.y, v1, acc0);
        acc0 = fmaf(t0.z, v2, acc0); acc0 = fmaf(t0.w, v3, acc0);
        acc1 = fmaf(t1.x, v0, acc1); acc1 = fmaf(t1.y, v1, acc1);
        acc1 = fmaf(t1.z, v2, acc1); acc1 = fmaf(t1.w, v3, acc1);
        acc2 = fmaf(t2.x, v0, acc2); acc2 = fmaf(t2.y, v1, acc2);
        acc2 = fmaf(t2.z, v2, acc2); acc2 = fmaf(t2.w, v3, acc2);
        acc3 = fmaf(t3.x, v0, acc3); acc3 = fmaf(t3.y, v1, acc3);
        acc3 = fmaf(t3.z, v2, acc3); acc3 = fmaf(t3.w, v3, acc3);
    }
    float* Ob = Opre + ((size_t)b * TT + x0) * NE + (size_t)h * NHD + d;
    Ob[(size_t)(mb + 0) * NE] = acc0 * rinv[mb + 0];
    Ob[(size_t)(mb + 1) * NE] = acc1 * rinv[mb + 1];
    Ob[(size_t)(mb + 2) * NE] = acc2 * rinv[mb + 2];
    Ob[(size_t)(mb + 3) * NE] = acc3 * rinv[mb + 3];
}

// -------------------------------------------------------------------------
// K3: final projection  Out[m, e] = sum_f X[m, f] * Wp[e, f] + bp[e]
// M = B*T = 2048, N = K = 512. 64x64 tiles, 256 threads, 4x4 per thread.
// -------------------------------------------------------------------------
__global__ __launch_bounds__(256, 4)
void k3_proj(const float* __restrict__ X, const float* __restrict__ Wp,
             const float* __restrict__ bp, float* __restrict__ Out)
{
    __shared__ float Xs[64][17];
    __shared__ float Ws[64][17];
    const int tid = threadIdx.x;
    const int m0 = blockIdx.x * 64;
    const int e0 = blockIdx.y * 64;
    const int tx = tid & 15, ty = tid >> 4;
    const int lr = tid >> 2;
    const int lc = (tid & 3) * 4;
    float acc[4][4] = {};
    for (int k0 = 0; k0 < NE; k0 += 16) {
        float4 xv = *(const float4*)&X[(size_t)(m0 + lr) * NE + k0 + lc];
        float4 wv = *(const float4*)&Wp[(size_t)(e0 + lr) * NE + k0 + lc];
        Xs[lr][lc + 0] = xv.x; Xs[lr][lc + 1] = xv.y;
        Xs[lr][lc + 2] = xv.z; Xs[lr][lc + 3] = xv.w;
        Ws[lr][lc + 0] = wv.x; Ws[lr][lc + 1] = wv.y;
        Ws[lr][lc + 2] = wv.z; Ws[lr][lc + 3] = wv.w;
        __syncthreads();
        #pragma unroll
        for (int k = 0; k < 16; ++k) {
            float xr[4], wr[4];
            #pragma unroll
            for (int i = 0; i < 4; ++i) xr[i] = Xs[ty * 4 + i][k];
            #pragma unroll
            for (int j = 0; j < 4; ++j) wr[j] = Ws[tx * 4 + j][k];
            #pragma unroll
            for (int i = 0; i < 4; ++i)
                #pragma unroll
                for (int j = 0; j < 4; ++j)
                    acc[i][j] = fmaf(xr[i], wr[j], acc[i][j]);
        }
        __syncthreads();
    }
    #pragma unroll
    for (int i = 0; i < 4; ++i) {
        float4 st;
        st.x = acc[i][0] + bp[e0 + tx * 4 + 0];
        st.y = acc[i][1] + bp[e0 + tx * 4 + 1];
        st.z = acc[i][2] + bp[e0 + tx * 4 + 2];
        st.w = acc[i][3] + bp[e0 + tx * 4 + 3];
        *(float4*)&Out[(size_t)(m0 + ty * 4 + i) * NE + e0 + tx * 4] = st;
    }
}

// -------------------------------------------------------------------------
extern "C" void kernel_launch(void* const* d_in, const int* in_sizes, int n_in,
                              void* d_out, int out_size, void* d_ws, size_t ws_size,
                              hipStream_t stream) {
    const float* A    = (const float*)d_in[0];
    // d_in[1] = Q, d_in[2] = K : unused by the reference computation
    const float* V    = (const float*)d_in[3];
    const float* Wexp = (const float*)d_in[4];
    const float* Wloc = (const float*)d_in[5];
    const float* bloc = (const float*)d_in[6];
    const float* Wred = (const float*)d_in[7];
    const float* Wp   = (const float*)d_in[8];
    const float* bp   = (const float*)d_in[9];

    // d_out = [out (B*T*E) | A_expanded (B*HP*T*T)] f32, in return order
    float* out_final = (float*)d_out;
    float* aexp = out_final + (size_t)NB * TT * NE;

    // workspace: A_reduced bf16 (33.5 MB) then out_pre f32 (4 MB)
    unsigned short* Ared = (unsigned short*)d_ws;
    float* Opre = (float*)((char*)d_ws + (size_t)NB * NH * TT * TT * 2);

    k1_fused<<<dim3(TT / CHX, TT / YB, NB), 256, 0, stream>>>(
        A, Wexp, Wloc, bloc, Wred, aexp, Ared);
    k2_softmax_pv<<<dim3(TT / MT, NH, NB), 256, 0, stream>>>(Ared, V, Opre);
    k3_proj<<<dim3((NB * TT) / 64, NE / 64), 256, 0, stream>>>(
        Opre, Wp, bp, out_final);
}

// Round 5
// 396.320 us; speedup vs baseline: 1.0948x; 1.0948x over previous
//
#include <hip/hip_runtime.h>
#include <hip/hip_bf16.h>

// Problem constants
#define TT  1024   // sequence length T
#define NH  8      // heads H
#define NHP 16     // expanded channels HP
#define NHD 64     // head dim
#define NE  512    // embed dim
#define NB  2      // batch
// k1 tiling: 256 threads = 256 columns, XR output rows per block
#define XR  8
#define YC  256
// k2 tiling
#define MT2 8      // rows per softmax/PV block

typedef unsigned short ushort8 __attribute__((ext_vector_type(8)));

__device__ __forceinline__ unsigned short f2bf(float f) {
    union { float f; unsigned u; } x; x.f = f;
    unsigned u = x.u;
    return (unsigned short)((u + 0x7FFFu + ((u >> 16) & 1u)) >> 16); // RNE
}
__device__ __forceinline__ float bf2f(unsigned short s) {
    union { unsigned u; float f; } x; x.u = ((unsigned)s) << 16;
    return x.f;
}

// -------------------------------------------------------------------------
// K1: fused expand + depthwise 3x3 + relu + reduce, register-accumulator
// formulation. Each thread owns one column y; vertical 3-tap partial sums
// live in registers (accM = pending for the row completing next, accN =
// pending for the row after). Per row, LDS holds ONE expanded row
// (pair-packed) purely for the +-1 column neighbor exchange:
//   per row per thread: 8 ds_write_b64 + 16 ds_read_b64 (vs 160 scalar ops
//   in the Round-3-measured stencil formulation). Eo stored from registers.
// A loads are prefetched one row ahead (hidden under ~440 VALU ops).
// Grid: (T/XR=128, T/YC=4, B) = 1024 blocks, LDS 33 KB -> 4 blocks/CU.
// -------------------------------------------------------------------------
__global__ __launch_bounds__(256, 4)
void k1_fused(const float* __restrict__ A,
              const float* __restrict__ Wexp,   // [16][8]
              const float* __restrict__ Wloc,   // [16][9]
              const float* __restrict__ bloc,   // [16]
              const float* __restrict__ Wred,   // [8][16]
              float* __restrict__ Eo_all,       // A_expanded out [B][16][T][T]
              unsigned short* __restrict__ Ared)// [B][8][T][T] bf16
{
    __shared__ float Es[2][NHP / 2][YC + 2][2];  // pair-packed E row, 2 slots
    const int tid = threadIdx.x;
    const int x0 = blockIdx.x * XR;
    const int ybase = blockIdx.y * YC;
    const int b = blockIdx.z;
    const int y = ybase + tid;
    const float* Ab = A + (size_t)b * NH * TT * TT;
    float* Eo = Eo_all + (size_t)b * NHP * TT * TT;
    unsigned short* Ar = Ared + (size_t)b * NH * TT * TT;

    // halo columns: thread 0 -> left edge (ybase-1), thread 255 -> right edge
    const bool isL = (tid == 0), isR = (tid == YC - 1);
    const bool isE = isL || isR;
    const int yE = isL ? (ybase - 1) : (ybase + YC);
    const int jE = isL ? 0 : (YC + 1);
    const bool eOK = isE && (yE >= 0) && (yE < TT);

    float accM[NHP];   // partial conv for output row r-1 (completes at row r)
    float accN[NHP];   // partial conv for output row r   (top taps + bias)
    float aN[NH], aNE[NH];

    // prefetch A for first processed row r = x0-1
    {
        const int r = x0 - 1;
        const bool vr = (r >= 0);
        #pragma unroll
        for (int h = 0; h < NH; ++h) {
            const size_t base = ((size_t)h * TT + r) * TT;
            aN[h]  = vr ? __builtin_nontemporal_load(&Ab[base + y]) : 0.f;
            aNE[h] = (vr && eOK) ? __builtin_nontemporal_load(&Ab[base + yE]) : 0.f;
        }
    }
    #pragma unroll
    for (int p = 0; p < NHP; ++p) { accM[p] = 0.f; accN[p] = 0.f; }

    for (int r = x0 - 1; r <= x0 + XR; ++r) {
        const int slot = (r - x0 + 1) & 1;
        // consume prefetched row, issue loads for the next one
        float aC[NH], aCE[NH];
        #pragma unroll
        for (int h = 0; h < NH; ++h) { aC[h] = aN[h]; aCE[h] = aNE[h]; }
        {
            const int rn = r + 1;
            const bool vn = (rn <= x0 + XR) && (rn < TT);
            #pragma unroll
            for (int h = 0; h < NH; ++h) {
                const size_t base = ((size_t)h * TT + rn) * TT;
                aN[h]  = vn ? __builtin_nontemporal_load(&Ab[base + y]) : 0.f;
                aNE[h] = (vn && eOK) ? __builtin_nontemporal_load(&Ab[base + yE]) : 0.f;
            }
        }
        // expand own column (zero rows give zero E == conv zero padding)
        float e[NHP];
        #pragma unroll
        for (int p = 0; p < NHP; ++p) {
            float s = 0.f;
            #pragma unroll
            for (int h = 0; h < NH; ++h) s = fmaf(Wexp[p * NH + h], aC[h], s);
            e[p] = s;
        }
        #pragma unroll
        for (int p2 = 0; p2 < NHP / 2; ++p2)
            *(float2*)&Es[slot][p2][tid + 1][0] =
                make_float2(e[2 * p2], e[2 * p2 + 1]);
        if (isE) {   // halo column (2 lanes per block)
            #pragma unroll
            for (int p2 = 0; p2 < NHP / 2; ++p2) {
                float s0 = 0.f, s1 = 0.f;
                #pragma unroll
                for (int h = 0; h < NH; ++h) {
                    s0 = fmaf(Wexp[(2 * p2) * NH + h], aCE[h], s0);
                    s1 = fmaf(Wexp[(2 * p2 + 1) * NH + h], aCE[h], s1);
                }
                *(float2*)&Es[slot][p2][jE][0] = make_float2(s0, s1);
            }
        }
        __syncthreads();   // single barrier per row (2-slot ring is safe)

        const bool doOut = (r > x0);
        float ar[NH];
        #pragma unroll
        for (int h = 0; h < NH; ++h) ar[h] = 0.f;
        #pragma unroll
        for (int p2 = 0; p2 < NHP / 2; ++p2) {
            const float2 l2 = *(const float2*)&Es[slot][p2][tid][0];
            const float2 r2 = *(const float2*)&Es[slot][p2][tid + 2][0];
            #pragma unroll
            for (int q = 0; q < 2; ++q) {
                const int p = 2 * p2 + q;
                const float eL = q ? l2.y : l2.x;
                const float eR = q ? r2.y : r2.x;
                const float eC = e[p];
                const float* wl = &Wloc[p * 9];
                if (doOut) {   // complete output row r-1 (bottom taps w6..w8)
                    float o = fmaf(wl[8], eR, fmaf(wl[7], eC,
                              fmaf(wl[6], eL, accM[p])));
                    o = fmaxf(o, 0.f);
                    #pragma unroll
                    for (int h = 0; h < NH; ++h)
                        ar[h] = fmaf(Wred[h * NHP + p], o, ar[h]);
                }
                // shift: accM <- accN + middle taps; accN <- top taps + bias
                accM[p] = fmaf(wl[5], eR, fmaf(wl[4], eC,
                          fmaf(wl[3], eL, accN[p])));
                accN[p] = fmaf(wl[2], eR, fmaf(wl[1], eC,
                          fmaf(wl[0], eL, bloc[p])));
            }
        }
        if (doOut) {
            const int xo = r - 1;
            #pragma unroll
            for (int h = 0; h < NH; ++h)
                Ar[((size_t)h * TT + xo) * TT + y] = f2bf(ar[h] * 0.125f);
        }
        if (r >= x0 && r < x0 + XR) {   // A_expanded from registers
            #pragma unroll
            for (int p = 0; p < NHP; ++p)
                __builtin_nontemporal_store(
                    e[p], &Eo[((size_t)p * TT + r) * TT + y]);
        }
    }
}

// -------------------------------------------------------------------------
// K2: row softmax + PV. MT2=8 rows/block; each wave owns 2 rows end-to-end
// (softmax AND PV) -> no cross-wave deps, ZERO barriers; 1/sum in registers.
// P stored unnormalized in bf16 LDS (16 KB) -> high occupancy; PV reads it
// as b128 broadcasts (free) and V as coalesced dwords, unrolled x8.
// Grid: (T/8=128, H, B) = 2048 blocks.
// -------------------------------------------------------------------------
__global__ __launch_bounds__(256, 6)
void k2_softmax_pv(const unsigned short* __restrict__ Ared,
                   const float* __restrict__ V,     // [B][H][T][64]
                   float* __restrict__ Opre)        // [B][T][E]
{
    __shared__ __align__(16) unsigned short ptile[MT2][TT];  // bf16 exp vals
    const int tid = threadIdx.x;
    const int lane = tid & 63;
    const int w = tid >> 6;
    const int x0 = blockIdx.x * MT2;
    const int h = blockIdx.y;
    const int b = blockIdx.z;
    const int mb = w * 2;   // this wave's two rows
    const unsigned short* Ab = Ared + (((size_t)b * NH + h) * TT + x0) * TT;

    // ---- softmax of rows mb, mb+1 (interleaved for ILP) ----
    const unsigned short* s0p = Ab + (size_t)(mb + 0) * TT;
    const unsigned short* s1p = Ab + (size_t)(mb + 1) * TT;
    float va[16], vb[16];
    #pragma unroll
    for (int c = 0; c < 4; ++c) {
        ushort4 u0 = *(const ushort4*)(s0p + c * 256 + lane * 4);
        ushort4 u1 = *(const ushort4*)(s1p + c * 256 + lane * 4);
        va[c*4+0] = bf2f(u0.x); va[c*4+1] = bf2f(u0.y);
        va[c*4+2] = bf2f(u0.z); va[c*4+3] = bf2f(u0.w);
        vb[c*4+0] = bf2f(u1.x); vb[c*4+1] = bf2f(u1.y);
        vb[c*4+2] = bf2f(u1.z); vb[c*4+3] = bf2f(u1.w);
    }
    float mx0 = -3.0e38f, mx1 = -3.0e38f;
    #pragma unroll
    for (int i = 0; i < 16; ++i) {
        mx0 = fmaxf(mx0, va[i]); mx1 = fmaxf(mx1, vb[i]);
    }
    #pragma unroll
    for (int off = 32; off > 0; off >>= 1) {
        mx0 = fmaxf(mx0, __shfl_xor(mx0, off, 64));
        mx1 = fmaxf(mx1, __shfl_xor(mx1, off, 64));
    }
    float sm0 = 0.f, sm1 = 0.f;
    #pragma unroll
    for (int i = 0; i < 16; ++i) {
        va[i] = __expf(va[i] - mx0); sm0 += va[i];
        vb[i] = __expf(vb[i] - mx1); sm1 += vb[i];
    }
    #pragma unroll
    for (int off = 32; off > 0; off >>= 1) {
        sm0 += __shfl_xor(sm0, off, 64);
        sm1 += __shfl_xor(sm1, off, 64);
    }
    const float inv0 = 1.f / sm0, inv1 = 1.f / sm1;
    #pragma unroll
    for (int c = 0; c < 4; ++c) {
        ushort4 q0, q1;
        q0.x = f2bf(va[c*4+0]); q0.y = f2bf(va[c*4+1]);
        q0.z = f2bf(va[c*4+2]); q0.w = f2bf(va[c*4+3]);
        q1.x = f2bf(vb[c*4+0]); q1.y = f2bf(vb[c*4+1]);
        q1.z = f2bf(vb[c*4+2]); q1.w = f2bf(vb[c*4+3]);
        *(ushort4*)&ptile[mb + 0][c * 256 + lane * 4] = q0;
        *(ushort4*)&ptile[mb + 1][c * 256 + lane * 4] = q1;
    }
    // no barrier: this wave reads back only its own two rows (lgkmcnt orders)

    // ---- PV: lane = output dim d ----
    const int d = lane;
    const float* Vb = V + ((size_t)b * NH + h) * TT * NHD + d;
    float acc0 = 0.f, acc1 = 0.f;
    for (int k = 0; k < TT; k += 8) {
        ushort8 q0 = *(const ushort8*)&ptile[mb + 0][k];   // broadcast read
        ushort8 q1 = *(const ushort8*)&ptile[mb + 1][k];
        float v[8];
        #pragma unroll
        for (int i = 0; i < 8; ++i) v[i] = Vb[(size_t)(k + i) * NHD];
        #pragma unroll
        for (int i = 0; i < 8; ++i) {
            acc0 = fmaf(bf2f(q0[i]), v[i], acc0);
            acc1 = fmaf(bf2f(q1[i]), v[i], acc1);
        }
    }
    float* Ob = Opre + ((size_t)b * TT + x0 + mb) * NE + (size_t)h * NHD + d;
    Ob[0]  = acc0 * inv0;
    Ob[NE] = acc1 * inv1;
}

// -------------------------------------------------------------------------
// K3: final projection  Out[m, e] = sum_f X[m, f] * Wp[e, f] + bp[e]
// M = B*T = 2048, N = K = 512. 64x64 tiles, 256 threads, 4x4 per thread.
// -------------------------------------------------------------------------
__global__ __launch_bounds__(256, 4)
void k3_proj(const float* __restrict__ X, const float* __restrict__ Wp,
             const float* __restrict__ bp, float* __restrict__ Out)
{
    __shared__ float Xs[64][17];
    __shared__ float Ws[64][17];
    const int tid = threadIdx.x;
    const int m0 = blockIdx.x * 64;
    const int e0 = blockIdx.y * 64;
    const int tx = tid & 15, ty = tid >> 4;
    const int lr = tid >> 2;
    const int lc = (tid & 3) * 4;
    float acc[4][4] = {};
    for (int k0 = 0; k0 < NE; k0 += 16) {
        float4 xv = *(const float4*)&X[(size_t)(m0 + lr) * NE + k0 + lc];
        float4 wv = *(const float4*)&Wp[(size_t)(e0 + lr) * NE + k0 + lc];
        Xs[lr][lc + 0] = xv.x; Xs[lr][lc + 1] = xv.y;
        Xs[lr][lc + 2] = xv.z; Xs[lr][lc + 3] = xv.w;
        Ws[lr][lc + 0] = wv.x; Ws[lr][lc + 1] = wv.y;
        Ws[lr][lc + 2] = wv.z; Ws[lr][lc + 3] = wv.w;
        __syncthreads();
        #pragma unroll
        for (int k = 0; k < 16; ++k) {
            float xr[4], wr[4];
            #pragma unroll
            for (int i = 0; i < 4; ++i) xr[i] = Xs[ty * 4 + i][k];
            #pragma unroll
            for (int j = 0; j < 4; ++j) wr[j] = Ws[tx * 4 + j][k];
            #pragma unroll
            for (int i = 0; i < 4; ++i)
                #pragma unroll
                for (int j = 0; j < 4; ++j)
                    acc[i][j] = fmaf(xr[i], wr[j], acc[i][j]);
        }
        __syncthreads();
    }
    #pragma unroll
    for (int i = 0; i < 4; ++i) {
        float4 st;
        st.x = acc[i][0] + bp[e0 + tx * 4 + 0];
        st.y = acc[i][1] + bp[e0 + tx * 4 + 1];
        st.z = acc[i][2] + bp[e0 + tx * 4 + 2];
        st.w = acc[i][3] + bp[e0 + tx * 4 + 3];
        *(float4*)&Out[(size_t)(m0 + ty * 4 + i) * NE + e0 + tx * 4] = st;
    }
}

// -------------------------------------------------------------------------
extern "C" void kernel_launch(void* const* d_in, const int* in_sizes, int n_in,
                              void* d_out, int out_size, void* d_ws, size_t ws_size,
                              hipStream_t stream) {
    const float* A    = (const float*)d_in[0];
    // d_in[1] = Q, d_in[2] = K : unused by the reference computation
    const float* V    = (const float*)d_in[3];
    const float* Wexp = (const float*)d_in[4];
    const float* Wloc = (const float*)d_in[5];
    const float* bloc = (const float*)d_in[6];
    const float* Wred = (const float*)d_in[7];
    const float* Wp   = (const float*)d_in[8];
    const float* bp   = (const float*)d_in[9];

    // d_out = [out (B*T*E) | A_expanded (B*HP*T*T)] f32, in return order
    float* out_final = (float*)d_out;
    float* aexp = out_final + (size_t)NB * TT * NE;

    // workspace: A_reduced bf16 (33.5 MB) then out_pre f32 (4 MB)
    unsigned short* Ared = (unsigned short*)d_ws;
    float* Opre = (float*)((char*)d_ws + (size_t)NB * NH * TT * TT * 2);

    k1_fused<<<dim3(TT / XR, TT / YC, NB), 256, 0, stream>>>(
        A, Wexp, Wloc, bloc, Wred, aexp, Ared);
    k2_softmax_pv<<<dim3(TT / MT2, NH, NB), 256, 0, stream>>>(Ared, V, Opre);
    k3_proj<<<dim3((NB * TT) / 64, NE / 64), 256, 0, stream>>>(
        Opre, Wp, bp, out_final);
}

// Round 7
// 354.287 us; speedup vs baseline: 1.2246x; 1.1186x over previous
//
#include <hip/hip_runtime.h>
#include <hip/hip_bf16.h>

// Problem constants
#define TT  1024   // sequence length T
#define NH  8      // heads H
#define NHP 16     // expanded channels HP
#define NHD 64     // head dim
#define NE  512    // embed dim
#define NB  2      // batch
// k1 tiling: 128 threads = 128 columns, XR output rows per block
#define XR  8
#define YC  128
// k2: 16 rows per block, 4 waves
#define K2M 16

typedef short short8v __attribute__((ext_vector_type(8)));
typedef float float4v __attribute__((ext_vector_type(4)));

__device__ __forceinline__ unsigned short f2bf(float f) {
    union { float f; unsigned u; } x; x.f = f;
    unsigned u = x.u;
    return (unsigned short)((u + 0x7FFFu + ((u >> 16) & 1u)) >> 16); // RNE
}
__device__ __forceinline__ float bf2f(unsigned short s) {
    union { unsigned u; float f; } x; x.u = ((unsigned)s) << 16;
    return x.f;
}

// -------------------------------------------------------------------------
// K1: fused expand + depthwise 3x3 + relu + reduce (register-accumulator,
// verified R5 at 101us/38% occupancy). Change: 128-thread blocks (YC=128)
// -> LDS 16.6 KB, 2048 blocks -> 8 resident blocks/CU (TLP for latency).
// -------------------------------------------------------------------------
__global__ __launch_bounds__(128, 4)
void k1_fused(const float* __restrict__ A,
              const float* __restrict__ Wexp,   // [16][8]
              const float* __restrict__ Wloc,   // [16][9]
              const float* __restrict__ bloc,   // [16]
              const float* __restrict__ Wred,   // [8][16]
              float* __restrict__ Eo_all,       // A_expanded out [B][16][T][T]
              unsigned short* __restrict__ Ared)// [B][8][T][T] bf16
{
    __shared__ float Es[2][NHP / 2][YC + 2][2];  // pair-packed E row, 2 slots
    const int tid = threadIdx.x;
    const int x0 = blockIdx.x * XR;
    const int ybase = blockIdx.y * YC;
    const int b = blockIdx.z;
    const int y = ybase + tid;
    const float* Ab = A + (size_t)b * NH * TT * TT;
    float* Eo = Eo_all + (size_t)b * NHP * TT * TT;
    unsigned short* Ar = Ared + (size_t)b * NH * TT * TT;

    const bool isL = (tid == 0), isR = (tid == YC - 1);
    const bool isE = isL || isR;
    const int yE = isL ? (ybase - 1) : (ybase + YC);
    const int jE = isL ? 0 : (YC + 1);
    const bool eOK = isE && (yE >= 0) && (yE < TT);

    float accM[NHP];   // partial conv for output row r-1 (completes at row r)
    float accN[NHP];   // partial conv for output row r   (top taps + bias)
    float aN[NH], aNE[NH];

    {
        const int r = x0 - 1;
        const bool vr = (r >= 0);
        #pragma unroll
        for (int h = 0; h < NH; ++h) {
            const size_t base = ((size_t)h * TT + r) * TT;
            aN[h]  = vr ? __builtin_nontemporal_load(&Ab[base + y]) : 0.f;
            aNE[h] = (vr && eOK) ? __builtin_nontemporal_load(&Ab[base + yE]) : 0.f;
        }
    }
    #pragma unroll
    for (int p = 0; p < NHP; ++p) { accM[p] = 0.f; accN[p] = 0.f; }

    for (int r = x0 - 1; r <= x0 + XR; ++r) {
        const int slot = (r - x0 + 1) & 1;
        float aC[NH], aCE[NH];
        #pragma unroll
        for (int h = 0; h < NH; ++h) { aC[h] = aN[h]; aCE[h] = aNE[h]; }
        {
            const int rn = r + 1;
            const bool vn = (rn <= x0 + XR) && (rn < TT);
            #pragma unroll
            for (int h = 0; h < NH; ++h) {
                const size_t base = ((size_t)h * TT + rn) * TT;
                aN[h]  = vn ? __builtin_nontemporal_load(&Ab[base + y]) : 0.f;
                aNE[h] = (vn && eOK) ? __builtin_nontemporal_load(&Ab[base + yE]) : 0.f;
            }
        }
        float e[NHP];
        #pragma unroll
        for (int p = 0; p < NHP; ++p) {
            float s = 0.f;
            #pragma unroll
            for (int h = 0; h < NH; ++h) s = fmaf(Wexp[p * NH + h], aC[h], s);
            e[p] = s;
        }
        #pragma unroll
        for (int p2 = 0; p2 < NHP / 2; ++p2)
            *(float2*)&Es[slot][p2][tid + 1][0] =
                make_float2(e[2 * p2], e[2 * p2 + 1]);
        if (isE) {
            #pragma unroll
            for (int p2 = 0; p2 < NHP / 2; ++p2) {
                float s0 = 0.f, s1 = 0.f;
                #pragma unroll
                for (int h = 0; h < NH; ++h) {
                    s0 = fmaf(Wexp[(2 * p2) * NH + h], aCE[h], s0);
                    s1 = fmaf(Wexp[(2 * p2 + 1) * NH + h], aCE[h], s1);
                }
                *(float2*)&Es[slot][p2][jE][0] = make_float2(s0, s1);
            }
        }
        __syncthreads();

        const bool doOut = (r > x0);
        float ar[NH];
        #pragma unroll
        for (int h = 0; h < NH; ++h) ar[h] = 0.f;
        #pragma unroll
        for (int p2 = 0; p2 < NHP / 2; ++p2) {
            const float2 l2 = *(const float2*)&Es[slot][p2][tid][0];
            const float2 r2 = *(const float2*)&Es[slot][p2][tid + 2][0];
            #pragma unroll
            for (int q = 0; q < 2; ++q) {
                const int p = 2 * p2 + q;
                const float eL = q ? l2.y : l2.x;
                const float eR = q ? r2.y : r2.x;
                const float eC = e[p];
                const float* wl = &Wloc[p * 9];
                if (doOut) {
                    float o = fmaf(wl[8], eR, fmaf(wl[7], eC,
                              fmaf(wl[6], eL, accM[p])));
                    o = fmaxf(o, 0.f);
                    #pragma unroll
                    for (int h = 0; h < NH; ++h)
                        ar[h] = fmaf(Wred[h * NHP + p], o, ar[h]);
                }
                accM[p] = fmaf(wl[5], eR, fmaf(wl[4], eC,
                          fmaf(wl[3], eL, accN[p])));
                accN[p] = fmaf(wl[2], eR, fmaf(wl[1], eC,
                          fmaf(wl[0], eL, bloc[p])));
            }
        }
        if (doOut) {
            const int xo = r - 1;
            #pragma unroll
            for (int h = 0; h < NH; ++h)
                Ar[((size_t)h * TT + xo) * TT + y] = f2bf(ar[h] * 0.125f);
        }
        if (r >= x0 && r < x0 + XR) {
            #pragma unroll
            for (int p = 0; p < NHP; ++p)
                __builtin_nontemporal_store(
                    e[p], &Eo[((size_t)p * TT + r) * TT + y]);
        }
    }
}

// -------------------------------------------------------------------------
// K2: softmax + PV via MFMA. Block = 16 rows of one (b,h), 4 waves.
// Phase 1: wave w softmaxes rows w*4..w*4+3, writes unnormalized bf16 P to
//   LDS with XOR swizzle byte^=((row&7)<<4) (2048B row stride would be a
//   16-way conflict unswizzled); 1/sum per row to LDS.
// Phase 2: 8 chunks of K=128: stage V chunk transposed bf16 Vt[64][136]
//   (272B stride -> uniform bank quads), 4x mfma_f32_16x16x32_bf16 per wave.
// Epilogue: scale by 1/sum, store f32.
// LDS 49.1 KB -> 3 blocks/CU. Grid 1024, XCD-chunked swizzle (64 blocks
// sharing V[b,h] land on one XCD's L2).
// -------------------------------------------------------------------------
#define PROWB 2048            // P row stride bytes (1024 cols * 2B)
#define VOFF  32768           // Vt base (16*2048)
#define VROWB 272             // Vt row stride bytes (136 ushorts)
#define ROFF  (VOFF + 64 * VROWB)   // rinv base
#define SMSZ  (ROFF + 64)

__global__ __launch_bounds__(256, 3)
void k2_softmax_pv(const unsigned short* __restrict__ Ared,
                   const float* __restrict__ V,     // [B][H][T][64]
                   float* __restrict__ Opre)        // [B][T][E] f32
{
    __shared__ __align__(16) char smc[SMSZ];
    char* sm = smc;
    const int tid = threadIdx.x;
    const int lane = tid & 63;
    const int w = tid >> 6;

    // XCD-chunked bijective swizzle: grid=1024, 8 XCDs, chunk=128
    const int hw = blockIdx.x;
    const int lg = (hw & 7) * 128 + (hw >> 3);
    const int b = lg >> 9;
    const int h = (lg >> 6) & 7;
    const int x0 = (lg & 63) << 4;

    const unsigned short* Ab = Ared + (((size_t)b * NH + h) * TT + x0) * TT;

    // ---- phase 1: softmax, 2 row-pairs per wave ----
    #pragma unroll
    for (int pp = 0; pp < 2; ++pp) {
        const int r0 = w * 4 + pp * 2;
        const unsigned short* s0p = Ab + (size_t)(r0 + 0) * TT;
        const unsigned short* s1p = Ab + (size_t)(r0 + 1) * TT;
        float va[16], vb[16];
        #pragma unroll
        for (int c = 0; c < 4; ++c) {
            ushort4 u0 = *(const ushort4*)(s0p + c * 256 + lane * 4);
            ushort4 u1 = *(const ushort4*)(s1p + c * 256 + lane * 4);
            va[c*4+0] = bf2f(u0.x); va[c*4+1] = bf2f(u0.y);
            va[c*4+2] = bf2f(u0.z); va[c*4+3] = bf2f(u0.w);
            vb[c*4+0] = bf2f(u1.x); vb[c*4+1] = bf2f(u1.y);
            vb[c*4+2] = bf2f(u1.z); vb[c*4+3] = bf2f(u1.w);
        }
        float mx0 = -3.0e38f, mx1 = -3.0e38f;
        #pragma unroll
        for (int i = 0; i < 16; ++i) {
            mx0 = fmaxf(mx0, va[i]); mx1 = fmaxf(mx1, vb[i]);
        }
        #pragma unroll
        for (int off = 32; off > 0; off >>= 1) {
            mx0 = fmaxf(mx0, __shfl_xor(mx0, off, 64));
            mx1 = fmaxf(mx1, __shfl_xor(mx1, off, 64));
        }
        float sm0 = 0.f, sm1 = 0.f;
        #pragma unroll
        for (int i = 0; i < 16; ++i) {
            va[i] = __expf(va[i] - mx0); sm0 += va[i];
            vb[i] = __expf(vb[i] - mx1); sm1 += vb[i];
        }
        #pragma unroll
        for (int off = 32; off > 0; off >>= 1) {
            sm0 += __shfl_xor(sm0, off, 64);
            sm1 += __shfl_xor(sm1, off, 64);
        }
        if (lane == 0) {
            *(float*)(sm + ROFF + (r0 + 0) * 4) = 1.f / sm0;
            *(float*)(sm + ROFF + (r0 + 1) * 4) = 1.f / sm1;
        }
        const int sz0 = ((r0 + 0) & 7) << 4;
        const int sz1 = ((r0 + 1) & 7) << 4;
        #pragma unroll
        for (int c = 0; c < 4; ++c) {
            ushort4 q0, q1;
            q0.x = f2bf(va[c*4+0]); q0.y = f2bf(va[c*4+1]);
            q0.z = f2bf(va[c*4+2]); q0.w = f2bf(va[c*4+3]);
            q1.x = f2bf(vb[c*4+0]); q1.y = f2bf(vb[c*4+1]);
            q1.z = f2bf(vb[c*4+2]); q1.w = f2bf(vb[c*4+3]);
            const int cb = c * 512 + lane * 8;
            *(ushort4*)(sm + ((r0 + 0) << 11) + (cb ^ sz0)) = q0;
            *(ushort4*)(sm + ((r0 + 1) << 11) + (cb ^ sz1)) = q1;
        }
    }
    __syncthreads();

    // ---- phase 2: PV via MFMA ----
    float4v acc = {0.f, 0.f, 0.f, 0.f};
    const int arow = lane & 15;          // A row / B col / D col
    const int kgrp = lane >> 4;          // k-subgroup 0..3
    const int abase = arow << 11;
    const int asz = (arow & 7) << 4;
    const int vrow = w * 16 + arow;      // V d-index for this wave's n-tile
    const float* Vb = V + ((size_t)b * NH + h) * TT * NHD;
    const int dstg = tid & 63;           // staging: d
    const int g = tid >> 6;              // staging: k-quarter

    for (int c = 0; c < 8; ++c) {
        const int kb = c * 128;
        #pragma unroll
        for (int j = 0; j < 16; ++j) {
            const int k2 = g * 32 + j * 2;
            const float f0 = Vb[(size_t)(kb + k2) * NHD + dstg];
            const float f1 = Vb[(size_t)(kb + k2 + 1) * NHD + dstg];
            const unsigned pk = (unsigned)f2bf(f0) | ((unsigned)f2bf(f1) << 16);
            *(unsigned*)(sm + VOFF + dstg * VROWB + k2 * 2) = pk;
        }
        __syncthreads();
        #pragma unroll
        for (int s = 0; s < 4; ++s) {
            const int colB = c * 256 + s * 64 + kgrp * 16; // byte of k*2
            short8v av = *(short8v*)(sm + abase + (colB ^ asz));
            short8v bv = *(short8v*)(sm + VOFF + vrow * VROWB + s * 64 + kgrp * 16);
            acc = __builtin_amdgcn_mfma_f32_16x16x32_bf16(av, bv, acc, 0, 0, 0);
        }
        __syncthreads();
    }

    // ---- epilogue: D[row=(kgrp*4+e)][col=arow], scale by 1/sum ----
    #pragma unroll
    for (int e = 0; e < 4; ++e) {
        const int row = kgrp * 4 + e;
        const float rv = *(const float*)(sm + ROFF + row * 4);
        Opre[((size_t)b * TT + x0 + row) * NE + (size_t)h * NHD + w * 16 + arow]
            = acc[e] * rv;
    }
}

// -------------------------------------------------------------------------
// K3: Out[m,e] = sum_f X[m,f] * Wp[e,f] + bp[e].  M=2048, N=K=512, f32.
// 64x32 tiles (4x2/thread), 512 blocks = 2/CU. LDS stride 20 floats:
// b128-aligned reads, spread banks.
// -------------------------------------------------------------------------
__global__ __launch_bounds__(256, 4)
void k3_proj(const float* __restrict__ X, const float* __restrict__ Wp,
             const float* __restrict__ bp, float* __restrict__ Out)
{
    __shared__ float Xs[64][20];
    __shared__ float Ws[32][20];
    const int tid = threadIdx.x;
    const int m0 = blockIdx.x * 64;
    const int e0 = blockIdx.y * 32;
    const int ty = tid >> 4;              // 0..15 -> 4 rows
    const int tx = tid & 15;              // 0..15 -> 2 cols
    const int xr = tid >> 2, xc = (tid & 3) * 4;
    const int wr = tid >> 3, wc = (tid & 7) * 2;
    float acc[4][2] = {};
    for (int k0 = 0; k0 < NE; k0 += 16) {
        *(float4*)&Xs[xr][xc] =
            *(const float4*)&X[(size_t)(m0 + xr) * NE + k0 + xc];
        *(float2*)&Ws[wr][wc] =
            *(const float2*)&Wp[(size_t)(e0 + wr) * NE + k0 + wc];
        __syncthreads();
        #pragma unroll
        for (int ks = 0; ks < 16; ks += 4) {
            float4 xq[4], wq[2];
            #pragma unroll
            for (int i = 0; i < 4; ++i)
                xq[i] = *(const float4*)&Xs[ty * 4 + i][ks];
            #pragma unroll
            for (int j = 0; j < 2; ++j)
                wq[j] = *(const float4*)&Ws[tx * 2 + j][ks];
            #pragma unroll
            for (int i = 0; i < 4; ++i)
                #pragma unroll
                for (int j = 0; j < 2; ++j) {
                    acc[i][j] = fmaf(xq[i].x, wq[j].x, acc[i][j]);
                    acc[i][j] = fmaf(xq[i].y, wq[j].y, acc[i][j]);
                    acc[i][j] = fmaf(xq[i].z, wq[j].z, acc[i][j]);
                    acc[i][j] = fmaf(xq[i].w, wq[j].w, acc[i][j]);
                }
        }
        __syncthreads();
    }
    #pragma unroll
    for (int i = 0; i < 4; ++i) {
        float2 st;
        st.x = acc[i][0] + bp[e0 + tx * 2 + 0];
        st.y = acc[i][1] + bp[e0 + tx * 2 + 1];
        *(float2*)&Out[(size_t)(m0 + ty * 4 + i) * NE + e0 + tx * 2] = st;
    }
}

// -------------------------------------------------------------------------
extern "C" void kernel_launch(void* const* d_in, const int* in_sizes, int n_in,
                              void* d_out, int out_size, void* d_ws, size_t ws_size,
                              hipStream_t stream) {
    const float* A    = (const float*)d_in[0];
    // d_in[1] = Q, d_in[2] = K : unused by the reference computation
    const float* V    = (const float*)d_in[3];
    const float* Wexp = (const float*)d_in[4];
    const float* Wloc = (const float*)d_in[5];
    const float* bloc = (const float*)d_in[6];
    const float* Wred = (const float*)d_in[7];
    const float* Wp   = (const float*)d_in[8];
    const float* bp   = (const float*)d_in[9];

    // d_out = [out (B*T*E) | A_expanded (B*HP*T*T)] f32, in return order
    float* out_final = (float*)d_out;
    float* aexp = out_final + (size_t)NB * TT * NE;

    // workspace: A_reduced bf16 (33.5 MB) then out_pre f32 (4 MB)
    unsigned short* Ared = (unsigned short*)d_ws;
    float* Opre = (float*)((char*)d_ws + (size_t)NB * NH * TT * TT * 2);

    k1_fused<<<dim3(TT / XR, TT / YC, NB), 128, 0, stream>>>(
        A, Wexp, Wloc, bloc, Wred, aexp, Ared);
    k2_softmax_pv<<<dim3((TT / K2M) * NH * NB), 256, 0, stream>>>(
        Ared, V, Opre);
    k3_proj<<<dim3((NB * TT) / 64, NE / 32), 256, 0, stream>>>(
        Opre, Wp, bp, out_final);
}